// Round 10
// baseline (505.388 us; speedup 1.0000x reference)
//
#include <hip/hip_runtime.h>
#include <stdint.h>

typedef __bf16    bf16x8 __attribute__((ext_vector_type(8)));
typedef _Float16  f16x8  __attribute__((ext_vector_type(8)));
typedef float     f32x4  __attribute__((ext_vector_type(4)));
typedef float     fvec4  __attribute__((ext_vector_type(4)));
typedef int       i32x4  __attribute__((ext_vector_type(4)));

#define EDIM   16
#define HIDDEN 64
#define MDIM   16
#define NDIM   16
#define KCHUNKS 32
#define NREP   8    // one output replica per XCD
#define WPB    8    // waves per block (512 threads)
// sHidT row stride (ushorts): 32 data + 4 pad -> bank spread, 8B-aligned rows
#define HROW   36
#define HPBLK  (16 * HROW)        // one parity block: 16 edges x 36
#define HGRP   (2 * HPBLK)        // per-wave region: 1152 ushorts

// ---------- fp16 helpers ----------
__device__ __forceinline__ ushort f16bits(float v) {
    return __builtin_bit_cast(ushort, (_Float16)v);
}
__device__ __forceinline__ uint32_t cvt_pk_f16(float x, float y) {
    return __builtin_bit_cast(uint32_t, __builtin_amdgcn_cvt_pkrtz(x, y));
}
__device__ __forceinline__ f16x8 u4_as_f16x8(uint32_t a, uint32_t b,
                                             uint32_t c, uint32_t d) {
    union { uint32_t u[4]; f16x8 v; } x;
    x.u[0] = a; x.u[1] = b; x.u[2] = c; x.u[3] = d;
    return x.v;
}
// packed f16 multiply, broadcasting ONE half of src0 to both products:
// HALF=0: d = {s0.lo*s1.lo, s0.lo*s1.hi}; HALF=1: same with s0.hi.
// -> scalar-hid x h-pair -> A-frag dword in ONE VALU instruction.
template<int HALF>
__device__ __forceinline__ uint32_t pkmul16(uint32_t hk, uint32_t h2) {
    uint32_t d;
    if (HALF)
        asm("v_pk_mul_f16 %0, %1, %2 op_sel:[1,0] op_sel_hi:[1,1]"
            : "=v"(d) : "v"(hk), "v"(h2));
    else
        asm("v_pk_mul_f16 %0, %1, %2 op_sel:[0,0] op_sel_hi:[0,1]"
            : "=v"(d) : "v"(hk), "v"(h2));
    return d;
}

// ---------- bf16 helpers (legacy fallback kernel only) ----------
__device__ __forceinline__ uint32_t pack_trunc(float x, float y) {
    return __builtin_amdgcn_perm(__builtin_bit_cast(uint32_t, x),
                                 __builtin_bit_cast(uint32_t, y),
                                 0x03020706u);
}
__device__ __forceinline__ uint16_t f32_to_bf16_rne(float f) {
    uint32_t u = __builtin_bit_cast(uint32_t, f);
    u += 0x7FFFu + ((u >> 16) & 1u);
    return (uint16_t)(u >> 16);
}
__device__ __forceinline__ bf16x8 u4_as_bf16x8(uint32_t a, uint32_t b,
                                               uint32_t c, uint32_t d) {
    union { uint32_t u[4]; bf16x8 v; } x;
    x.u[0] = a; x.u[1] = b; x.u[2] = c; x.u[3] = d;
    return x.v;
}

// L2-local fp32 atomic add, saddr form (no sc bits -> XCD-local TCC RMW).
__device__ __forceinline__ void atomic_add_s(const float* base, uint32_t off,
                                             float v) {
    asm volatile("global_atomic_add_f32 %0, %1, %2"
                 :: "v"(off), "v"(v), "s"(base) : "memory");
}

__device__ __forceinline__ void load_eh(const float* p, uint32_t ro,
                                        fvec4& a, fvec4& b) {
    const fvec4* pp = (const fvec4*)(p + ro);
    a = __builtin_nontemporal_load(pp);
    b = __builtin_nontemporal_load(pp + 1);
}

__device__ __forceinline__ i32x4 load_idx4(const int* __restrict__ idx,
                                           int r, int n_edge, bool full) {
    i32x4 v;
    if (full) {
        v = __builtin_nontemporal_load((const i32x4*)(idx + r));
    } else {
        v.x = __builtin_nontemporal_load(idx + min(r + 0, n_edge - 1));
        v.y = __builtin_nontemporal_load(idx + min(r + 1, n_edge - 1));
        v.z = __builtin_nontemporal_load(idx + min(r + 2, n_edge - 1));
        v.w = __builtin_nontemporal_load(idx + min(r + 3, n_edge - 1));
    }
    return v;
}

// hid stage (fp16) for one 16-edge group: 4 MFMAs, relu, scalar-cvt,
// transpose-write into sHidT [p=k&1][e][kk=k>>1] (k = nt*16+col).
__device__ __forceinline__ void hid_stage_f16(fvec4 ea, fvec4 eb, int q,
                                              const f16x8* w1f,
                                              ushort* wrBase) {
    uint32_t au0 = cvt_pk_f16(ea.x, ea.y);
    uint32_t au1 = cvt_pk_f16(ea.z, ea.w);
    uint32_t au2 = cvt_pk_f16(eb.x, eb.y);
    uint32_t au3 = cvt_pk_f16(eb.z, eb.w);
    if (q == 2) { au0 = 0x00003C00u; au1 = au2 = au3 = 0; } // bias row: 1.0 f16
    else if (q == 3) { au0 = au1 = au2 = au3 = 0; }
    f16x8 av = u4_as_f16x8(au0, au1, au2, au3);
    #pragma unroll
    for (int nt = 0; nt < 4; nt++) {
        f32x4 hc = {0.f, 0.f, 0.f, 0.f};
        hc = __builtin_amdgcn_mfma_f32_16x16x32_f16(av, w1f[nt], hc, 0, 0, 0);
        // value = hid[e=q*4+i][k=nt*16+col] -> p=col&1, kk=nt*8+(col>>1)
        #pragma unroll
        for (int i = 0; i < 4; i++)
            wrBase[i * HROW + nt * 8] = f16bits(fmaxf(hc[i], 0.f));
    }
}

// Per 32-edge tile (one wave, two 16-edge groups sharing each B-fragment):
//   hid-GEMM x2 (fp16) -> hid transposed via sHidT -> BULK-read into 32 VGPRs
//   (8 x b64 per group; the two groups time-share ONE per-wave sHidT region).
//   big GEMM: 32 chunks, pure-register A-frag build: v_pk_mul_f16 op_sel
//   selects the even/odd fp16 hid half at COMPILE TIME -> 4 VALU per
//   group-chunk, no per-chunk LDS reads, no packs. One sB ds_read_b128
//   feeds both groups' MFMAs.
// LDS = 32KB sB(fp16) + 18KB sHidT = 51.2KB -> 3 blocks/CU (24 waves, 75%).
// Scatter: per-XCD replica (HW_REG_XCC_ID) + L2-local atomics; merge kernel
// sums 8 replicas. All next-tile loads issue BEFORE this tile's atomics.
__global__ __launch_bounds__(512, 6) void msg_mfma32_f16(
    const int*   __restrict__ idx,
    const float* __restrict__ h_w,
    const float* __restrict__ e_vw,
    const float* __restrict__ W1,   // [16][64]
    const float* __restrict__ b1,   // [64]
    const float* __restrict__ W2,   // [64][256]  ([k][m*16+n])
    const float* __restrict__ b2,   // [256]      ([m*16+n])
    float*       __restrict__ outb, // [NREP][n_node*16] pre-zeroed
    int n_edge, int rep_stride)
{
    // B-fragment-ordered W2 (fp16): sB[c][q][m][j] = W2[2c+(q>>1)][m*16+(q&1)*8+j]
    __align__(16) __shared__ ushort sB[KCHUNKS * 512];     // 32768 B
    // per-wave hid transpose, [p][e][kk] rows padded to HROW
    __align__(16) __shared__ ushort sHidT[WPB * HGRP];     // 18432 B

    const int tid = threadIdx.x;

    // ---- per-XCD output replica (HW_REG_XCC_ID = id 20, size 4) ----
    const int xcd = __builtin_amdgcn_s_getreg(6164) & (NREP - 1);
    const float* out = outb + (size_t)xcd * (size_t)rep_stride;

    // ---- stage W2 fragments (fp16, once per block) ----
    for (int t = tid; t < KCHUNKS * 512; t += 512) {
        int c = t >> 9, r = t & 511;
        int qq = r >> 7, m = (r >> 3) & 15, j = r & 7;
        int k = 2 * c + (qq >> 1);
        int n = ((qq & 1) << 3) + j;
        sB[t] = f16bits(W2[k * 256 + m * 16 + n]);
    }

    const int lane = tid & 63;
    const int q    = lane >> 4;
    const int col  = lane & 15;
    const int w    = tid >> 6;

    // ---- W1ext B-fragments (fp16, once per wave) ----
    uint32_t w1u[4][4];
    #pragma unroll
    for (int nt = 0; nt < 4; nt++) {
        #pragma unroll
        for (int d = 0; d < 4; d++) w1u[nt][d] = 0;
        #pragma unroll
        for (int j = 0; j < 8; j++) {
            int k = q * 8 + j;
            float v = 0.f;
            if (k < 16)       v = W1[k * 64 + nt * 16 + col];
            else if (k == 16) v = b1[nt * 16 + col];
            w1u[nt][j >> 1] |= ((uint32_t)f16bits(v)) << ((j & 1) * 16);
        }
    }
    // ---- b2 B-fragment (fp16): q<2 -> b2, q>=2 -> 0 ----
    uint32_t b2u[4] = {0, 0, 0, 0};
    if (q < 2) {
        const float* bp = b2 + col * 16 + q * 8;
        #pragma unroll
        for (int j = 0; j < 8; j++)
            b2u[j >> 1] |= ((uint32_t)f16bits(bp[j])) << ((j & 1) * 16);
    }
    __syncthreads();

    f16x8 w1f[4];
    #pragma unroll
    for (int nt = 0; nt < 4; nt++)
        w1f[nt] = u4_as_f16x8(w1u[nt][0], w1u[nt][1], w1u[nt][2], w1u[nt][3]);
    const f16x8 b2f = u4_as_f16x8(b2u[0], b2u[1], b2u[2], b2u[3]);

    const int nhalf = (q & 1) << 3;
    const int ntile = (n_edge + 31) >> 5;
    const int wave_id = blockIdx.x * WPB + w;
    const int wstride = gridDim.x * WPB;
    if (wave_id >= ntile) return;

    // sHidT lane pointers (per-wave region, time-shared by both groups)
    ushort* hWr = &sHidT[w * HGRP + (col & 1) * HPBLK + (q * 4) * HROW + (col >> 1)];
    const ushort* hRd = &sHidT[w * HGRP + (q >> 1) * HPBLK + col * HROW];
    const ushort* bRd = &sB[q * 128 + col * 8];            // + c*512
    const uint32_t col4 = (uint32_t)col * 4u;

    // ---- initial tile load ----
    int t = wave_id;
    fvec4 e0, e1, e2, e3, h0, h1, h2, h3; i32x4 nd0, nd1; bool full;
    {
        int rbase = t * 32;
        full = (rbase + 32 <= n_edge);
        int row0 = full ? (rbase + col)      : min(rbase + col,      n_edge - 1);
        int row1 = full ? (rbase + 16 + col) : min(rbase + 16 + col, n_edge - 1);
        uint32_t ro0 = (uint32_t)row0 * 16u + (uint32_t)nhalf;
        uint32_t ro1 = (uint32_t)row1 * 16u + (uint32_t)nhalf;
        load_eh(e_vw, ro0, e0, e1);
        load_eh(e_vw, ro1, e2, e3);
        load_eh(h_w,  ro0, h0, h1);
        load_eh(h_w,  ro1, h2, h3);
        nd0 = load_idx4(idx, rbase + q * 4,      n_edge, full);
        nd1 = load_idx4(idx, rbase + 16 + q * 4, n_edge, full);
    }

    while (true) {
        int tn = t + wstride;
        bool have_next = (tn < ntile);

        // ---- group 0: hid stage -> bulk-read hid into registers ----
        hid_stage_f16(e0, e1, q, w1f, hWr);
        uint32_t hv0[16];
        #pragma unroll
        for (int j = 0; j < 8; j++) {
            uint2 t2 = *(const uint2*)(hRd + j * 4);
            hv0[2 * j] = t2.x; hv0[2 * j + 1] = t2.y;
        }
        // ---- group 1: overwrite same region -> bulk-read ----
        hid_stage_f16(e2, e3, q, w1f, hWr);
        uint32_t hv1[16];
        #pragma unroll
        for (int j = 0; j < 8; j++) {
            uint2 t2 = *(const uint2*)(hRd + j * 4);
            hv1[2 * j] = t2.x; hv1[2 * j + 1] = t2.y;
        }

        // ---- e-prefetch next tile (e dead), BEFORE atomics ----
        bool nfull = false;
        if (have_next) {
            int rbase = tn * 32;
            nfull = (rbase + 32 <= n_edge);
            int row0 = nfull ? (rbase + col)      : min(rbase + col,      n_edge - 1);
            int row1 = nfull ? (rbase + 16 + col) : min(rbase + 16 + col, n_edge - 1);
            load_eh(e_vw, (uint32_t)row0 * 16u + (uint32_t)nhalf, e0, e1);
            load_eh(e_vw, (uint32_t)row1 * 16u + (uint32_t)nhalf, e2, e3);
        }

        // h as fp16 pairs (A-frag src1 operands)
        uint32_t hF0 = cvt_pk_f16(h0.x, h0.y), hF1 = cvt_pk_f16(h0.z, h0.w);
        uint32_t hF2 = cvt_pk_f16(h1.x, h1.y), hF3 = cvt_pk_f16(h1.z, h1.w);
        uint32_t hG0 = cvt_pk_f16(h2.x, h2.y), hG1 = cvt_pk_f16(h2.z, h2.w);
        uint32_t hG2 = cvt_pk_f16(h3.x, h3.y), hG3 = cvt_pk_f16(h3.z, h3.w);

        // ---- bias MFMAs: A = h (fp16 pairs, directly), B = b2 frag ----
        f32x4 acc0 = {0.f, 0.f, 0.f, 0.f};
        f32x4 acc1 = {0.f, 0.f, 0.f, 0.f};
        acc0 = __builtin_amdgcn_mfma_f32_16x16x32_f16(
                   u4_as_f16x8(hF0, hF1, hF2, hF3), b2f, acc0, 0, 0, 0);
        acc1 = __builtin_amdgcn_mfma_f32_16x16x32_f16(
                   u4_as_f16x8(hG0, hG1, hG2, hG3), b2f, acc1, 0, 0, 0);

        // ---- big GEMM: 32 chunks; hid from REGISTERS (op_sel half-select),
        //      one sB b128 read feeds both groups ----
        #pragma unroll
        for (int d = 0; d < 16; d++) {
            {   // chunk 2d: even fp16 half of hv[d]
                f16x8 bfb = *(const f16x8*)(bRd + (2 * d) * 512);
                f16x8 a0 = u4_as_f16x8(pkmul16<0>(hv0[d], hF0), pkmul16<0>(hv0[d], hF1),
                                       pkmul16<0>(hv0[d], hF2), pkmul16<0>(hv0[d], hF3));
                acc0 = __builtin_amdgcn_mfma_f32_16x16x32_f16(a0, bfb, acc0, 0, 0, 0);
                f16x8 a1 = u4_as_f16x8(pkmul16<0>(hv1[d], hG0), pkmul16<0>(hv1[d], hG1),
                                       pkmul16<0>(hv1[d], hG2), pkmul16<0>(hv1[d], hG3));
                acc1 = __builtin_amdgcn_mfma_f32_16x16x32_f16(a1, bfb, acc1, 0, 0, 0);
            }
            {   // chunk 2d+1: odd fp16 half of hv[d]
                f16x8 bfb = *(const f16x8*)(bRd + (2 * d + 1) * 512);
                f16x8 a0 = u4_as_f16x8(pkmul16<1>(hv0[d], hF0), pkmul16<1>(hv0[d], hF1),
                                       pkmul16<1>(hv0[d], hF2), pkmul16<1>(hv0[d], hF3));
                acc0 = __builtin_amdgcn_mfma_f32_16x16x32_f16(a0, bfb, acc0, 0, 0, 0);
                f16x8 a1 = u4_as_f16x8(pkmul16<1>(hv1[d], hG0), pkmul16<1>(hv1[d], hG1),
                                       pkmul16<1>(hv1[d], hG2), pkmul16<1>(hv1[d], hG3));
                acc1 = __builtin_amdgcn_mfma_f32_16x16x32_f16(a1, bfb, acc1, 0, 0, 0);
            }
        }

        // ---- h + nd prefetch next (h dead), BEFORE atomics ----
        i32x4 ndn0, ndn1;
        if (have_next) {
            int rbase = tn * 32;
            int row0 = nfull ? (rbase + col)      : min(rbase + col,      n_edge - 1);
            int row1 = nfull ? (rbase + 16 + col) : min(rbase + 16 + col, n_edge - 1);
            load_eh(h_w, (uint32_t)row0 * 16u + (uint32_t)nhalf, h0, h1);
            load_eh(h_w, (uint32_t)row1 * 16u + (uint32_t)nhalf, h2, h3);
            ndn0 = load_idx4(idx, rbase + q * 4,      n_edge, nfull);
            ndn1 = load_idx4(idx, rbase + 16 + q * 4, n_edge, nfull);
        }

        // ---- epilogue: L2-local atomics (replica single-XCD-writer) ----
        if (full) {
            atomic_add_s(out, (uint32_t)nd0.x * 64u + col4, acc0[0]);
            atomic_add_s(out, (uint32_t)nd0.y * 64u + col4, acc0[1]);
            atomic_add_s(out, (uint32_t)nd0.z * 64u + col4, acc0[2]);
            atomic_add_s(out, (uint32_t)nd0.w * 64u + col4, acc0[3]);
            atomic_add_s(out, (uint32_t)nd1.x * 64u + col4, acc1[0]);
            atomic_add_s(out, (uint32_t)nd1.y * 64u + col4, acc1[1]);
            atomic_add_s(out, (uint32_t)nd1.z * 64u + col4, acc1[2]);
            atomic_add_s(out, (uint32_t)nd1.w * 64u + col4, acc1[3]);
        } else {
            int r0 = t * 32 + q * 4;
            int r1 = r0 + 16;
            if (r0 + 0 < n_edge) atomic_add_s(out, (uint32_t)nd0.x * 64u + col4, acc0[0]);
            if (r0 + 1 < n_edge) atomic_add_s(out, (uint32_t)nd0.y * 64u + col4, acc0[1]);
            if (r0 + 2 < n_edge) atomic_add_s(out, (uint32_t)nd0.z * 64u + col4, acc0[2]);
            if (r0 + 3 < n_edge) atomic_add_s(out, (uint32_t)nd0.w * 64u + col4, acc0[3]);
            if (r1 + 0 < n_edge) atomic_add_s(out, (uint32_t)nd1.x * 64u + col4, acc1[0]);
            if (r1 + 1 < n_edge) atomic_add_s(out, (uint32_t)nd1.y * 64u + col4, acc1[1]);
            if (r1 + 2 < n_edge) atomic_add_s(out, (uint32_t)nd1.z * 64u + col4, acc1[2]);
            if (r1 + 3 < n_edge) atomic_add_s(out, (uint32_t)nd1.w * 64u + col4, acc1[3]);
        }

        if (!have_next) break;
        t = tn; full = nfull; nd0 = ndn0; nd1 = ndn1;
    }
}

// ---- legacy fallback (ws too small): bf16 16-edge kernel, device atomics ----
__device__ __forceinline__ void hid_stage_bf16(fvec4 ea, fvec4 eb, int q,
                                               const bf16x8* w1f, ushort* hidWr) {
    uint32_t au0 = pack_trunc(ea.x, ea.y);
    uint32_t au1 = pack_trunc(ea.z, ea.w);
    uint32_t au2 = pack_trunc(eb.x, eb.y);
    uint32_t au3 = pack_trunc(eb.z, eb.w);
    if (q == 2) { au0 = 0x00003F80u; au1 = au2 = au3 = 0; }
    else if (q == 3) { au0 = au1 = au2 = au3 = 0; }
    bf16x8 av = u4_as_bf16x8(au0, au1, au2, au3);
    #pragma unroll
    for (int nt = 0; nt < 4; nt++) {
        f32x4 hc = {0.f, 0.f, 0.f, 0.f};
        hc = __builtin_amdgcn_mfma_f32_16x16x32_bf16(av, w1f[nt], hc, 0, 0, 0);
        uint32_t lo = pack_trunc(fmaxf(hc[0], 0.f), fmaxf(hc[1], 0.f));
        uint32_t hi = pack_trunc(fmaxf(hc[2], 0.f), fmaxf(hc[3], 0.f));
        *(uint2*)(hidWr + nt * 256) = make_uint2(lo, hi);
    }
}

__global__ __launch_bounds__(512, 6) void msg_mfma_legacy(
    const int*   __restrict__ idx,
    const float* __restrict__ h_w,
    const float* __restrict__ e_vw,
    const float* __restrict__ W1,
    const float* __restrict__ b1,
    const float* __restrict__ W2,
    const float* __restrict__ b2,
    float*       __restrict__ out,
    int n_edge)
{
    __align__(16) __shared__ ushort sB[KCHUNKS * 512];
    __align__(16) __shared__ ushort sHid[WPB * 64 * 16];
    const int tid = threadIdx.x;
    for (int t = tid; t < KCHUNKS * 512; t += 512) {
        int c = t >> 9, r = t & 511;
        int qq = r >> 7, m = (r >> 3) & 15, j = r & 7;
        int k = 2 * c + (qq >> 1);
        int n = ((qq & 1) << 3) + j;
        sB[t] = f32_to_bf16_rne(W2[k * 256 + m * 16 + n]);
    }
    const int lane = tid & 63, q = lane >> 4, col = lane & 15, w = tid >> 6;
    uint32_t w1u[4][4];
    #pragma unroll
    for (int nt = 0; nt < 4; nt++) {
        #pragma unroll
        for (int d = 0; d < 4; d++) w1u[nt][d] = 0;
        #pragma unroll
        for (int j = 0; j < 8; j++) {
            int k = q * 8 + j;
            float v = 0.f;
            if (k < 16)       v = W1[k * 64 + nt * 16 + col];
            else if (k == 16) v = b1[nt * 16 + col];
            w1u[nt][j >> 1] |= ((uint32_t)f32_to_bf16_rne(v)) << ((j & 1) * 16);
        }
    }
    uint32_t b2u[4] = {0, 0, 0, 0};
    if (q < 2) {
        const float* bp = b2 + col * 16 + q * 8;
        #pragma unroll
        for (int j = 0; j < 8; j++)
            b2u[j >> 1] |= ((uint32_t)f32_to_bf16_rne(bp[j])) << ((j & 1) * 16);
    }
    __syncthreads();
    bf16x8 w1f[4];
    #pragma unroll
    for (int nt = 0; nt < 4; nt++)
        w1f[nt] = u4_as_bf16x8(w1u[nt][0], w1u[nt][1], w1u[nt][2], w1u[nt][3]);
    const bf16x8 b2f = u4_as_bf16x8(b2u[0], b2u[1], b2u[2], b2u[3]);
    const int nhalf = (q & 1) << 3;
    const int ntile = (n_edge + 15) >> 4;
    int t = blockIdx.x * WPB + w;
    const int wstride = gridDim.x * WPB;
    const ushort* hidRd = &sHid[w * 1024 + (q >> 1) * 16 + col];
    ushort*       hidWr = &sHid[w * 1024 + col * 16 + q * 4];
    const ushort* bRd   = &sB[q * 128 + col * 8];
    for (; t < ntile; t += wstride) {
        int row = min(t * 16 + col, n_edge - 1);
        const fvec4* ep = (const fvec4*)(e_vw + (size_t)row * 16 + nhalf);
        fvec4 e0 = ep[0], e1 = ep[1];
        const fvec4* hpp = (const fvec4*)(h_w + (size_t)row * 16 + nhalf);
        fvec4 h0 = hpp[0], h1 = hpp[1];
        int r0 = t * 16 + q * 4;
        int4 nd;
        nd.x = idx[min(r0 + 0, n_edge - 1)];
        nd.y = idx[min(r0 + 1, n_edge - 1)];
        nd.z = idx[min(r0 + 2, n_edge - 1)];
        nd.w = idx[min(r0 + 3, n_edge - 1)];
        hid_stage_bf16(e0, e1, q, w1f, hidWr);
        float hf[8] = {h0.x, h0.y, h0.z, h0.w, h1.x, h1.y, h1.z, h1.w};
        f32x4 acc = {0.f, 0.f, 0.f, 0.f};
        {
            uint32_t a0 = pack_trunc(hf[0], hf[1]);
            uint32_t a1 = pack_trunc(hf[2], hf[3]);
            uint32_t a2 = pack_trunc(hf[4], hf[5]);
            uint32_t a3 = pack_trunc(hf[6], hf[7]);
            acc = __builtin_amdgcn_mfma_f32_16x16x32_bf16(
                u4_as_bf16x8(a0, a1, a2, a3), b2f, acc, 0, 0, 0);
        }
        #pragma unroll
        for (int c = 0; c < KCHUNKS; c++) {
            uint32_t hku = ((uint32_t)hidRd[c * 32]) << 16;
            float hk = __builtin_bit_cast(float, hku);
            uint32_t a0 = pack_trunc(hk * hf[0], hk * hf[1]);
            uint32_t a1 = pack_trunc(hk * hf[2], hk * hf[3]);
            uint32_t a2 = pack_trunc(hk * hf[4], hk * hf[5]);
            uint32_t a3 = pack_trunc(hk * hf[6], hk * hf[7]);
            bf16x8 bfb = *(const bf16x8*)(bRd + c * 512);
            acc = __builtin_amdgcn_mfma_f32_16x16x32_bf16(
                u4_as_bf16x8(a0, a1, a2, a3), bfb, acc, 0, 0, 0);
        }
        if (r0 + 0 < n_edge) atomicAdd(out + (size_t)nd.x * 16 + col, acc[0]);
        if (r0 + 1 < n_edge) atomicAdd(out + (size_t)nd.y * 16 + col, acc[1]);
        if (r0 + 2 < n_edge) atomicAdd(out + (size_t)nd.z * 16 + col, acc[2]);
        if (r0 + 3 < n_edge) atomicAdd(out + (size_t)nd.w * 16 + col, acc[3]);
    }
}

// out[i] = sum over the 8 per-XCD replicas. 51.2MB read + 6.4MB write.
__global__ void merge_rep(const fvec4* __restrict__ rep,
                          fvec4* __restrict__ out, int n4, int stride4)
{
    int i = blockIdx.x * blockDim.x + threadIdx.x;
    if (i >= n4) return;
    fvec4 s = rep[i];
    #pragma unroll
    for (int r = 1; r < NREP; r++)
        s += rep[(size_t)r * stride4 + i];
    out[i] = s;
}

extern "C" void kernel_launch(void* const* d_in, const int* in_sizes, int n_in,
                              void* d_out, int out_size, void* d_ws, size_t ws_size,
                              hipStream_t stream) {
    const int*   idx  = (const int*)  d_in[0];
    const float* h_w  = (const float*)d_in[1];
    const float* e_vw = (const float*)d_in[2];
    const float* W1   = (const float*)d_in[4];
    const float* b1   = (const float*)d_in[5];
    const float* W2   = (const float*)d_in[6];
    const float* b2   = (const float*)d_in[7];
    float* out = (float*)d_out;
    const int n_edge = in_sizes[0];

    const size_t out_floats = (size_t)out_size;           // n_node * 16
    const size_t need = (size_t)NREP * out_floats * sizeof(float);

    if (ws_size >= need && (out_floats & 3) == 0) {
        float* rep = (float*)d_ws;
        (void)hipMemsetAsync(rep, 0, need, stream);
        // 768 blocks = exactly 3 resident blocks per CU (51.2KB LDS each)
        msg_mfma32_f16<<<768, 512, 0, stream>>>(idx, h_w, e_vw, W1, b1, W2, b2,
                                                rep, n_edge, (int)out_floats);
        const int n4 = (int)(out_floats >> 2);
        const int mblocks = (n4 + 255) / 256;
        merge_rep<<<mblocks, 256, 0, stream>>>((const fvec4*)rep, (fvec4*)out,
                                               n4, n4);
    } else {
        (void)hipMemsetAsync(out, 0, out_floats * sizeof(float), stream);
        msg_mfma_legacy<<<1536, 512, 0, stream>>>(idx, h_w, e_vw, W1, b1, W2,
                                                  b2, out, n_edge);
    }
}